// Round 1
// baseline (429.761 us; speedup 1.0000x reference)
//
#include <hip/hip_runtime.h>
#include <cstdint>
#include <cstddef>

// Problem constants (B=4, L=1024)
#define DM 1024      // D_MODEL
#define EI 2048      // E_INNER
#define NS 16        // N_STATE
#define DR 64        // DT_RANK
#define BB 4
#define LL 1024
#define MM (BB*LL)   // 4096 token rows
#define NCHUNK 16
#define CHUNK 64

typedef __attribute__((ext_vector_type(8))) __bf16 bf16x8;
typedef __attribute__((ext_vector_type(4))) float f32x4;

__device__ __forceinline__ unsigned short f2bf(float f) {
    union { float f; unsigned int u; } v; v.f = f;
    unsigned int r = v.u + 0x7FFFu + ((v.u >> 16) & 1u);   // RNE
    return (unsigned short)(r >> 16);
}

__device__ __forceinline__ void gload_lds16(const unsigned short* g, unsigned short* l) {
    __builtin_amdgcn_global_load_lds(
        (const __attribute__((address_space(1))) unsigned int*)g,
        (__attribute__((address_space(3))) unsigned int*)l, 16, 0, 0);
}

// ---------------- RMSNorm -> bf16 ----------------
__global__ void rmsnorm_bf16(const float* __restrict__ x, const float* __restrict__ w,
                             unsigned short* __restrict__ out) {
    int m = blockIdx.x, tid = threadIdx.x;
    const float4* row = (const float4*)(x + (size_t)m * DM);
    float4 v = row[tid];
    float ss = v.x*v.x + v.y*v.y + v.z*v.z + v.w*v.w;
    #pragma unroll
    for (int o = 32; o; o >>= 1) ss += __shfl_down(ss, o);
    __shared__ float red[4];
    if ((tid & 63) == 0) red[tid >> 6] = ss;
    __syncthreads();
    ss = red[0] + red[1] + red[2] + red[3];
    float scale = rsqrtf(ss * (1.0f / DM) + 1e-6f);
    const float4* wr = (const float4*)w;
    float4 wv = wr[tid];
    ushort4 o4;
    o4.x = f2bf(v.x * scale * wv.x);
    o4.y = f2bf(v.y * scale * wv.y);
    o4.z = f2bf(v.z * scale * wv.z);
    o4.w = f2bf(v.w * scale * wv.w);
    ((ushort4*)out)[(size_t)m * (DM/4) + tid] = o4;
}

// ---------------- transpose fp32 (R,C) -> bf16 (C,R) ----------------
__global__ void transpose_f2bf(const float* __restrict__ in, unsigned short* __restrict__ out,
                               int R, int C) {
    __shared__ float t[32][33];
    int c0 = blockIdx.x * 32, r0 = blockIdx.y * 32;
    int tx = threadIdx.x, ty = threadIdx.y;
    #pragma unroll
    for (int j = 0; j < 32; j += 8) {
        int r = r0 + ty + j, c = c0 + tx;
        if (r < R && c < C) t[ty + j][tx] = in[(size_t)r * C + c];
    }
    __syncthreads();
    #pragma unroll
    for (int j = 0; j < 32; j += 8) {
        int c = c0 + ty + j, r = r0 + tx;
        if (c < C && r < R) out[(size_t)c * R + r] = f2bf(t[tx][ty + j]);
    }
}

// ---------------- MFMA GEMM: C[M,N] = A[M,K](bf16) * Bt[N,K](bf16)^T ----------------
// EPI 0: plain fp32 store   1: + residual   2: softplus(v+bias)   3: split x_db -> (dtlr bf16, bc f32)
template<int EPI>
__global__ void gemm_mfma(const unsigned short* __restrict__ A,
                          const unsigned short* __restrict__ Bt,
                          float* __restrict__ C,
                          const float* __restrict__ ex1,
                          float* __restrict__ ex2,
                          unsigned short* __restrict__ exb,
                          int M, int N, int K, int ldc) {
    __shared__ __attribute__((aligned(16))) unsigned short lds_a[128 * 32];
    __shared__ __attribute__((aligned(16))) unsigned short lds_b[128 * 32];
    const int tid = threadIdx.x;
    const int w = tid >> 6, lane = tid & 63;
    const int m0 = blockIdx.y * 128, n0 = blockIdx.x * 128;
    const int wm = (w & 1) * 64, wn = (w >> 1) * 64;
    const int q = lane >> 4, r = lane & 15;
    const int srow = lane >> 2;          // 0..15
    const int scol = (lane & 3) * 8;     // 0,8,16,24

    f32x4 acc[4][4];
    f32x4 zero = {0.f, 0.f, 0.f, 0.f};
    #pragma unroll
    for (int i = 0; i < 4; ++i) {
        #pragma unroll
        for (int j = 0; j < 4; ++j) acc[i][j] = zero;
    }

    for (int kb = 0; kb < K; kb += 32) {
        __syncthreads();
        #pragma unroll
        for (int j = 0; j < 2; ++j) {
            int rbase = w * 32 + j * 16;
            gload_lds16(A  + (size_t)(m0 + rbase + srow) * K + kb + scol, lds_a + rbase * 32);
            gload_lds16(Bt + (size_t)(n0 + rbase + srow) * K + kb + scol, lds_b + rbase * 32);
        }
        __syncthreads();
        bf16x8 af[4], bf[4];
        #pragma unroll
        for (int mi = 0; mi < 4; ++mi)
            af[mi] = *(const bf16x8*)(lds_a + (wm + mi * 16 + r) * 32 + q * 8);
        #pragma unroll
        for (int ni = 0; ni < 4; ++ni)
            bf[ni] = *(const bf16x8*)(lds_b + (wn + ni * 16 + r) * 32 + q * 8);
        #pragma unroll
        for (int mi = 0; mi < 4; ++mi) {
            #pragma unroll
            for (int ni = 0; ni < 4; ++ni)
                acc[mi][ni] = __builtin_amdgcn_mfma_f32_16x16x32_bf16(af[mi], bf[ni], acc[mi][ni], 0, 0, 0);
        }
    }

    #pragma unroll
    for (int mi = 0; mi < 4; ++mi) {
        #pragma unroll
        for (int ni = 0; ni < 4; ++ni) {
            f32x4 v = acc[mi][ni];
            int gmb = m0 + wm + mi * 16 + q * 4;
            int gn  = n0 + wn + ni * 16 + r;
            #pragma unroll
            for (int t = 0; t < 4; ++t) {
                int gm = gmb + t;
                float val = v[t];
                if (EPI == 0) {
                    C[(size_t)gm * ldc + gn] = val;
                } else if (EPI == 1) {
                    C[(size_t)gm * ldc + gn] = val + ex1[(size_t)gm * ldc + gn];
                } else if (EPI == 2) {
                    val += ex1[gn];
                    val = fmaxf(val, 0.f) + log1pf(__expf(-fabsf(val)));
                    C[(size_t)gm * ldc + gn] = val;
                } else {
                    if (gn < DR) exb[(size_t)gm * DR + gn] = f2bf(val);
                    else if (gn < DR + 2 * NS) ex2[(size_t)gm * (2 * NS) + (gn - DR)] = val;
                }
            }
        }
    }
}

// ---------------- causal depthwise conv(K=4) + SiLU ----------------
__global__ void conv_silu(const float* __restrict__ xz, const float* __restrict__ cw,
                          float* __restrict__ xaf, unsigned short* __restrict__ xab) {
    size_t idx = (size_t)blockIdx.x * 256 + threadIdx.x;   // m*2048 + e
    int e = (int)(idx & (EI - 1));
    size_t m = idx >> 11;
    int l = (int)(m & (LL - 1));
    const float* base = xz + m * 4096 + e;     // x_in lives in xz cols [0,2048)
    float w0 = cw[e*4+0], w1 = cw[e*4+1], w2 = cw[e*4+2], w3 = cw[e*4+3];
    float s = base[0] * w3;
    if (l >= 1) s += base[-1 * 4096] * w2;
    if (l >= 2) s += base[-2 * 4096] * w1;
    if (l >= 3) s += base[-3 * 4096] * w0;
    float a = s / (1.f + __expf(-s));
    xaf[idx] = a;
    xab[idx] = f2bf(a);
}

// ---------------- selective scan, 3-phase chunked ----------------
__global__ void scan_phase1(const float* __restrict__ xz, const float* __restrict__ xact,
                            const float* __restrict__ bc, const float* __restrict__ A_log,
                            float* __restrict__ P, float* __restrict__ H) {
    int e = blockIdx.x * 256 + threadIdx.x;
    int c = blockIdx.y, b = blockIdx.z;
    float A[NS], h[NS], p[NS];
    #pragma unroll
    for (int n = 0; n < NS; ++n) {
        A[n] = -expf(A_log[(size_t)e * NS + n]);
        h[n] = 0.f; p[n] = 1.f;
    }
    int mbase = b * LL + c * CHUNK;
    for (int t = 0; t < CHUNK; ++t) {
        size_t m = (size_t)(mbase + t);
        float d = xz[m * 4096 + e];
        float u = xact[m * 2048 + e];
        float du = d * u;
        const float* Bv = bc + m * 32;
        #pragma unroll
        for (int n = 0; n < NS; ++n) {
            float dA = __expf(d * A[n]);
            p[n] *= dA;
            h[n] = fmaf(dA, h[n], du * Bv[n]);
        }
    }
    size_t base = ((size_t)(b * NCHUNK + c) * NS) * 2048 + e;
    #pragma unroll
    for (int n = 0; n < NS; ++n) {
        P[base + (size_t)n * 2048] = p[n];
        H[base + (size_t)n * 2048] = h[n];
    }
}

__global__ void scan_phase2(const float* __restrict__ P, const float* __restrict__ H,
                            float* __restrict__ h0, float* __restrict__ hlast) {
    int id = blockIdx.x * 256 + threadIdx.x;   // b*2048+e
    int b = id >> 11, e = id & (EI - 1);
    float h[NS];
    #pragma unroll
    for (int n = 0; n < NS; ++n) h[n] = 0.f;
    for (int c = 0; c < NCHUNK; ++c) {
        size_t base = ((size_t)(b * NCHUNK + c) * NS) * 2048 + e;
        #pragma unroll
        for (int n = 0; n < NS; ++n) {
            size_t ix = base + (size_t)n * 2048;
            h0[ix] = h[n];
            h[n] = fmaf(P[ix], h[n], H[ix]);
        }
    }
    float* hl = hlast + (size_t)id * NS;
    #pragma unroll
    for (int n = 0; n < NS; ++n) hl[n] = h[n];
}

__global__ void scan_phase3(const float* __restrict__ xz, const float* __restrict__ xact,
                            const float* __restrict__ bc, const float* __restrict__ A_log,
                            const float* __restrict__ Dp, const float* __restrict__ h0,
                            unsigned short* __restrict__ ybf) {
    int e = blockIdx.x * 256 + threadIdx.x;
    int c = blockIdx.y, b = blockIdx.z;
    float A[NS], h[NS];
    size_t base = ((size_t)(b * NCHUNK + c) * NS) * 2048 + e;
    #pragma unroll
    for (int n = 0; n < NS; ++n) {
        A[n] = -expf(A_log[(size_t)e * NS + n]);
        h[n] = h0[base + (size_t)n * 2048];
    }
    float D = Dp[e];
    int mbase = b * LL + c * CHUNK;
    for (int t = 0; t < CHUNK; ++t) {
        size_t m = (size_t)(mbase + t);
        float d = xz[m * 4096 + e];
        float u = xact[m * 2048 + e];
        float du = d * u;
        const float* Bv = bc + m * 32;
        float y = 0.f;
        #pragma unroll
        for (int n = 0; n < NS; ++n) {
            float dA = __expf(d * A[n]);
            h[n] = fmaf(dA, h[n], du * Bv[n]);
            y = fmaf(h[n], Bv[16 + n], y);
        }
        y = fmaf(u, D, y);
        float z = xz[m * 4096 + 2048 + e];
        float sil = z / (1.f + __expf(-z));
        ybf[m * 2048 + e] = f2bf(y * sil);
    }
}

extern "C" void kernel_launch(void* const* d_in, const int* in_sizes, int n_in,
                              void* d_out, int out_size, void* d_ws, size_t ws_size,
                              hipStream_t stream) {
    (void)in_sizes; (void)n_in; (void)out_size; (void)ws_size;
    const float* hidden = (const float*)d_in[0];
    const float* norm_w = (const float*)d_in[1];
    const float* W_in   = (const float*)d_in[2];
    const float* conv_w = (const float*)d_in[3];
    // d_in[4] = W_x, d_in[5] = W_dt
    const float* W_x    = (const float*)d_in[4];
    const float* W_dt   = (const float*)d_in[5];
    const float* b_dt   = (const float*)d_in[6];
    const float* A_log  = (const float*)d_in[7];
    const float* D_par  = (const float*)d_in[8];
    const float* W_out  = (const float*)d_in[9];
    float* out = (float*)d_out;
    char* ws = (char*)d_ws;
    const size_t MB = 1ull << 20;

    float*          xz       = (float*)(ws + 0);                    // 64 MB (x_in|z, later delta|z)
    float*          xact_f   = (float*)(ws + 64 * MB);              // 32 MB
    unsigned short* xact_bf  = (unsigned short*)(ws + 96 * MB);     // 16 MB, reused: h0 after GEMM2
    unsigned short* xnorm_bf = (unsigned short*)(ws + 112 * MB);    //  8 MB, reused: P after GEMM1
    unsigned short* wt_in    = (unsigned short*)(ws + 120 * MB);    //  8 MB, reused: H after GEMM1
    unsigned short* wt_out   = (unsigned short*)(ws + 128 * MB);    //  4 MB
    unsigned short* wt_x     = (unsigned short*)(ws + 132 * MB);    // 512 KB (padded to 128 rows)
    unsigned short* wt_dt    = (unsigned short*)(ws + 132 * MB + 512 * 1024); // 256 KB
    unsigned short* dtlr     = (unsigned short*)(ws + 133 * MB);    // 512 KB
    float*          bc       = (float*)(ws + 133 * MB + 512 * 1024);// 512 KB
    unsigned short* ybf      = (unsigned short*)(ws + 134 * MB);    // 16 MB  (total 150 MB)
    float* P  = (float*)xnorm_bf;
    float* Hb = (float*)wt_in;
    float* h0 = (float*)xact_bf;
    float* hlast = out + (size_t)MM * DM;

    dim3 tb(32, 8);
    rmsnorm_bf16<<<MM, 256, 0, stream>>>(hidden, norm_w, xnorm_bf);
    transpose_f2bf<<<dim3(4096/32, 1024/32), tb, 0, stream>>>(W_in, wt_in, 1024, 4096);
    transpose_f2bf<<<dim3(3, 2048/32), tb, 0, stream>>>(W_x, wt_x, 2048, 96);
    transpose_f2bf<<<dim3(2048/32, 2), tb, 0, stream>>>(W_dt, wt_dt, 64, 2048);
    transpose_f2bf<<<dim3(1024/32, 2048/32), tb, 0, stream>>>(W_out, wt_out, 2048, 1024);

    // xz = rmsnorm(x) @ W_in   (M=4096, N=4096, K=1024)
    gemm_mfma<0><<<dim3(32, 32), 256, 0, stream>>>(xnorm_bf, wt_in, xz, nullptr, nullptr, nullptr,
                                                   MM, 4096, 1024, 4096);
    // x_act = silu(dwconv(x_in))
    conv_silu<<<(MM * EI) / 256, 256, 0, stream>>>(xz, conv_w, xact_f, xact_bf);
    // x_db = x_act @ W_x -> split (dtlr bf16 | bc f32), N padded 96->128
    gemm_mfma<3><<<dim3(1, 32), 256, 0, stream>>>(xact_bf, wt_x, nullptr, nullptr, bc, dtlr,
                                                  MM, 128, 2048, 0);
    // delta = softplus(dtlr @ W_dt + b_dt) written into xz cols [0,2048) (ldc=4096)
    gemm_mfma<2><<<dim3(16, 32), 256, 0, stream>>>(dtlr, wt_dt, xz, b_dt, nullptr, nullptr,
                                                   MM, 2048, 64, 4096);
    // chunked selective scan
    scan_phase1<<<dim3(8, NCHUNK, BB), 256, 0, stream>>>(xz, xact_f, bc, A_log, P, Hb);
    scan_phase2<<<32, 256, 0, stream>>>(P, Hb, h0, hlast);
    scan_phase3<<<dim3(8, NCHUNK, BB), 256, 0, stream>>>(xz, xact_f, bc, A_log, D_par, h0, ybf);
    // out = residual + y @ W_out  (M=4096, N=1024, K=2048)
    gemm_mfma<1><<<dim3(8, 32), 256, 0, stream>>>(ybf, wt_out, out, hidden, nullptr, nullptr,
                                                  MM, 1024, 2048, 1024);
}

// Round 2
// 351.522 us; speedup vs baseline: 1.2226x; 1.2226x over previous
//
#include <hip/hip_runtime.h>
#include <cstdint>
#include <cstddef>

// Problem constants (B=4, L=1024)
#define DM 1024      // D_MODEL
#define EI 2048      // E_INNER
#define NS 16        // N_STATE
#define DR 64        // DT_RANK
#define BB 4
#define LL 1024
#define MM (BB*LL)   // 4096 token rows
#define NCHUNK 16
#define CHUNK 64

typedef __attribute__((ext_vector_type(8))) __bf16 bf16x8;
typedef __attribute__((ext_vector_type(4))) float f32x4;

__device__ __forceinline__ unsigned short f2bf(float f) {
    union { float f; unsigned int u; } v; v.f = f;
    unsigned int r = v.u + 0x7FFFu + ((v.u >> 16) & 1u);   // RNE
    return (unsigned short)(r >> 16);
}
__device__ __forceinline__ float bf2f(unsigned short u) {
    union { unsigned int u; float f; } v; v.u = ((unsigned int)u) << 16;
    return v.f;
}

__device__ __forceinline__ void gload_lds16(const unsigned short* g, unsigned short* l) {
    __builtin_amdgcn_global_load_lds(
        (const __attribute__((address_space(1))) unsigned int*)g,
        (__attribute__((address_space(3))) unsigned int*)l, 16, 0, 0);
}

// ---------------- RMSNorm -> bf16 ----------------
__global__ void rmsnorm_bf16(const float* __restrict__ x, const float* __restrict__ w,
                             unsigned short* __restrict__ out) {
    int m = blockIdx.x, tid = threadIdx.x;
    const float4* row = (const float4*)(x + (size_t)m * DM);
    float4 v = row[tid];
    float ss = v.x*v.x + v.y*v.y + v.z*v.z + v.w*v.w;
    #pragma unroll
    for (int o = 32; o; o >>= 1) ss += __shfl_down(ss, o);
    __shared__ float red[4];
    if ((tid & 63) == 0) red[tid >> 6] = ss;
    __syncthreads();
    ss = red[0] + red[1] + red[2] + red[3];
    float scale = rsqrtf(ss * (1.0f / DM) + 1e-6f);
    const float4* wr = (const float4*)w;
    float4 wv = wr[tid];
    ushort4 o4;
    o4.x = f2bf(v.x * scale * wv.x);
    o4.y = f2bf(v.y * scale * wv.y);
    o4.z = f2bf(v.z * scale * wv.z);
    o4.w = f2bf(v.w * scale * wv.w);
    ((ushort4*)out)[(size_t)m * (DM/4) + tid] = o4;
}

// ---------------- transpose fp32 (R,C) -> bf16 (C,R) ----------------
__global__ void transpose_f2bf(const float* __restrict__ in, unsigned short* __restrict__ out,
                               int R, int C) {
    __shared__ float t[32][33];
    int c0 = blockIdx.x * 32, r0 = blockIdx.y * 32;
    int tx = threadIdx.x, ty = threadIdx.y;
    #pragma unroll
    for (int j = 0; j < 32; j += 8) {
        int r = r0 + ty + j, c = c0 + tx;
        if (r < R && c < C) t[ty + j][tx] = in[(size_t)r * C + c];
    }
    __syncthreads();
    #pragma unroll
    for (int j = 0; j < 32; j += 8) {
        int c = c0 + ty + j, r = r0 + tx;
        if (c < C && r < R) out[(size_t)c * R + r] = f2bf(t[tx][ty + j]);
    }
}

// ---------------- MFMA GEMM: C[M,N] = A[M,K](bf16) * Bt[N,K](bf16)^T ----------------
// EPI 1: fp32 store + residual      (out-proj)
// EPI 2: fp32 store softplus(v+b)   (delta-proj)
// EPI 3: split-K partial fp32, grid.x = 8 k-slices, single 128-wide N tile (x-proj)
// EPI 4: bf16 store                 (in-proj)
template<int EPI>
__global__ void gemm_mfma(const unsigned short* __restrict__ A,
                          const unsigned short* __restrict__ Bt,
                          float* __restrict__ C,
                          const float* __restrict__ ex1,
                          unsigned short* __restrict__ exb,
                          int M, int N, int K, int ldc) {
    __shared__ __attribute__((aligned(16))) unsigned short lds_a[128 * 32];
    __shared__ __attribute__((aligned(16))) unsigned short lds_b[128 * 32];
    const int tid = threadIdx.x;
    const int w = tid >> 6, lane = tid & 63;
    const int m0 = blockIdx.y * 128;
    const int n0 = (EPI == 3) ? 0 : blockIdx.x * 128;
    const int kstart = (EPI == 3) ? blockIdx.x * (K >> 3) : 0;
    const int kend   = (EPI == 3) ? kstart + (K >> 3) : K;
    const int wm = (w & 1) * 64, wn = (w >> 1) * 64;
    const int q = lane >> 4, r = lane & 15;
    const int srow = lane >> 2;          // 0..15
    const int scol = (lane & 3) * 8;     // 0,8,16,24

    f32x4 acc[4][4];
    f32x4 zero = {0.f, 0.f, 0.f, 0.f};
    #pragma unroll
    for (int i = 0; i < 4; ++i)
        #pragma unroll
        for (int j = 0; j < 4; ++j) acc[i][j] = zero;

    for (int kb = kstart; kb < kend; kb += 32) {
        __syncthreads();
        #pragma unroll
        for (int j = 0; j < 2; ++j) {
            int rbase = w * 32 + j * 16;
            gload_lds16(A  + (size_t)(m0 + rbase + srow) * K + kb + scol, lds_a + rbase * 32);
            gload_lds16(Bt + (size_t)(n0 + rbase + srow) * K + kb + scol, lds_b + rbase * 32);
        }
        __syncthreads();
        bf16x8 af[4], bfr[4];
        #pragma unroll
        for (int mi = 0; mi < 4; ++mi)
            af[mi] = *(const bf16x8*)(lds_a + (wm + mi * 16 + r) * 32 + q * 8);
        #pragma unroll
        for (int ni = 0; ni < 4; ++ni)
            bfr[ni] = *(const bf16x8*)(lds_b + (wn + ni * 16 + r) * 32 + q * 8);
        #pragma unroll
        for (int mi = 0; mi < 4; ++mi)
            #pragma unroll
            for (int ni = 0; ni < 4; ++ni)
                acc[mi][ni] = __builtin_amdgcn_mfma_f32_16x16x32_bf16(af[mi], bfr[ni], acc[mi][ni], 0, 0, 0);
    }

    #pragma unroll
    for (int mi = 0; mi < 4; ++mi) {
        #pragma unroll
        for (int ni = 0; ni < 4; ++ni) {
            f32x4 v = acc[mi][ni];
            int gmb = m0 + wm + mi * 16 + q * 4;
            int gn  = n0 + wn + ni * 16 + r;
            #pragma unroll
            for (int t = 0; t < 4; ++t) {
                int gm = gmb + t;
                float val = v[t];
                if (EPI == 1) {
                    C[(size_t)gm * ldc + gn] = val + ex1[(size_t)gm * ldc + gn];
                } else if (EPI == 2) {
                    val += ex1[gn];
                    val = fmaxf(val, 0.f) + log1pf(__expf(-fabsf(val)));
                    C[(size_t)gm * ldc + gn] = val;
                } else if (EPI == 3) {
                    C[((size_t)blockIdx.x * M + gm) * 128 + gn] = val;
                } else {
                    exb[(size_t)gm * ldc + gn] = f2bf(val);
                }
            }
        }
    }
}

// ---------------- split-K reduce for x-proj: sum 8 partials, split dtlr/bc ----------------
__global__ void xproj_reduce(const float* __restrict__ Pp,
                             unsigned short* __restrict__ dtlr, float* __restrict__ bc) {
    int id = blockIdx.x * 256 + threadIdx.x;   // 4096*128
    int n = id & 127, m = id >> 7;
    if (n >= DR + 2 * NS) return;
    float s = 0.f;
    #pragma unroll
    for (int ks = 0; ks < 8; ++ks)
        s += Pp[((size_t)ks * MM + m) * 128 + n];
    if (n < DR) dtlr[(size_t)m * DR + n] = f2bf(s);
    else bc[(size_t)m * 32 + (n - DR)] = s;
}

// ---------------- causal depthwise conv(K=4) + SiLU (bf16 in/out) ----------------
__global__ void conv_silu(const unsigned short* __restrict__ xzb, const float* __restrict__ cw,
                          unsigned short* __restrict__ xab) {
    size_t idx = (size_t)blockIdx.x * 256 + threadIdx.x;   // m*2048 + e
    int e = (int)(idx & (EI - 1));
    size_t m = idx >> 11;
    int l = (int)(m & (LL - 1));
    const unsigned short* base = xzb + m * 4096 + e;       // x_in = cols [0,2048)
    float w0 = cw[e*4+0], w1 = cw[e*4+1], w2 = cw[e*4+2], w3 = cw[e*4+3];
    float s = bf2f(base[0]) * w3;
    if (l >= 1) s += bf2f(base[-1 * 4096]) * w2;
    if (l >= 2) s += bf2f(base[-2 * 4096]) * w1;
    if (l >= 3) s += bf2f(base[-3 * 4096]) * w0;
    float a = s / (1.f + __expf(-s));
    xab[idx] = f2bf(a);
}

// ---------------- selective scan, 3-phase chunked ----------------
__global__ void scan_phase1(const float* __restrict__ dbuf, const unsigned short* __restrict__ xu,
                            const float* __restrict__ bc, const float* __restrict__ A_log,
                            float* __restrict__ P, float* __restrict__ H) {
    int e = blockIdx.x * 256 + threadIdx.x;
    int c = blockIdx.y, b = blockIdx.z;
    float A[NS], h[NS], p[NS];
    #pragma unroll
    for (int n = 0; n < NS; ++n) {
        A[n] = -expf(A_log[(size_t)e * NS + n]);
        h[n] = 0.f; p[n] = 1.f;
    }
    int mbase = b * LL + c * CHUNK;
    for (int t = 0; t < CHUNK; ++t) {
        size_t m = (size_t)(mbase + t);
        float d = dbuf[m * 2048 + e];
        float u = bf2f(xu[m * 2048 + e]);
        float du = d * u;
        const float* Bv = bc + m * 32;
        #pragma unroll
        for (int n = 0; n < NS; ++n) {
            float dA = __expf(d * A[n]);
            p[n] *= dA;
            h[n] = fmaf(dA, h[n], du * Bv[n]);
        }
    }
    size_t base = ((size_t)(b * NCHUNK + c) * NS) * 2048 + e;
    #pragma unroll
    for (int n = 0; n < NS; ++n) {
        P[base + (size_t)n * 2048] = p[n];
        H[base + (size_t)n * 2048] = h[n];
    }
}

// one thread per (b,n,e): coalesced over e, 131072 threads
__global__ void scan_phase2(const float* __restrict__ P, const float* __restrict__ H,
                            float* __restrict__ h0, float* __restrict__ hlast) {
    int id = blockIdx.x * 256 + threadIdx.x;
    int e = id & (EI - 1);
    int bn = id >> 11;
    int n = bn & (NS - 1), b = bn >> 4;
    float h = 0.f;
    #pragma unroll
    for (int c = 0; c < NCHUNK; ++c) {
        size_t ix = (((size_t)(b * NCHUNK + c) * NS) + n) * 2048 + e;
        h0[ix] = h;
        h = fmaf(P[ix], h, H[ix]);
    }
    hlast[(((size_t)b * EI + e) * NS) + n] = h;
}

__global__ void scan_phase3(const float* __restrict__ dbuf, const unsigned short* __restrict__ xu,
                            const unsigned short* __restrict__ xzb,
                            const float* __restrict__ bc, const float* __restrict__ A_log,
                            const float* __restrict__ Dp, const float* __restrict__ h0,
                            unsigned short* __restrict__ ybf) {
    int e = blockIdx.x * 256 + threadIdx.x;
    int c = blockIdx.y, b = blockIdx.z;
    float A[NS], h[NS];
    size_t base = ((size_t)(b * NCHUNK + c) * NS) * 2048 + e;
    #pragma unroll
    for (int n = 0; n < NS; ++n) {
        A[n] = -expf(A_log[(size_t)e * NS + n]);
        h[n] = h0[base + (size_t)n * 2048];
    }
    float D = Dp[e];
    int mbase = b * LL + c * CHUNK;
    for (int t = 0; t < CHUNK; ++t) {
        size_t m = (size_t)(mbase + t);
        float d = dbuf[m * 2048 + e];
        float u = bf2f(xu[m * 2048 + e]);
        float du = d * u;
        const float* Bv = bc + m * 32;
        float y = 0.f;
        #pragma unroll
        for (int n = 0; n < NS; ++n) {
            float dA = __expf(d * A[n]);
            h[n] = fmaf(dA, h[n], du * Bv[n]);
            y = fmaf(h[n], Bv[16 + n], y);
        }
        y = fmaf(u, D, y);
        float z = bf2f(xzb[m * 4096 + 2048 + e]);
        float sil = z / (1.f + __expf(-z));
        ybf[m * 2048 + e] = f2bf(y * sil);
    }
}

extern "C" void kernel_launch(void* const* d_in, const int* in_sizes, int n_in,
                              void* d_out, int out_size, void* d_ws, size_t ws_size,
                              hipStream_t stream) {
    (void)in_sizes; (void)n_in; (void)out_size; (void)ws_size;
    const float* hidden = (const float*)d_in[0];
    const float* norm_w = (const float*)d_in[1];
    const float* W_in   = (const float*)d_in[2];
    const float* conv_w = (const float*)d_in[3];
    const float* W_x    = (const float*)d_in[4];
    const float* W_dt   = (const float*)d_in[5];
    const float* b_dt   = (const float*)d_in[6];
    const float* A_log  = (const float*)d_in[7];
    const float* D_par  = (const float*)d_in[8];
    const float* W_out  = (const float*)d_in[9];
    float* out = (float*)d_out;
    char* ws = (char*)d_ws;
    const size_t MB = 1ull << 20;

    unsigned short* xzb      = (unsigned short*)(ws + 0);            // 32 MB bf16 (x_in|z)
    unsigned short* xact_bf  = (unsigned short*)(ws + 32 * MB);      // 16 MB
    unsigned short* xnorm_bf = (unsigned short*)(ws + 48 * MB);      //  8 MB
    unsigned short* wt_in    = (unsigned short*)(ws + 56 * MB);      //  8 MB
    unsigned short* wt_out   = (unsigned short*)(ws + 64 * MB);      //  4 MB
    unsigned short* wt_x     = (unsigned short*)(ws + 68 * MB);      // 512 KB (padded 96->128 rows)
    unsigned short* wt_dt    = (unsigned short*)(ws + 68 * MB + 512 * 1024);  // 256 KB
    unsigned short* dtlr     = (unsigned short*)(ws + 69 * MB);      // 512 KB
    float*          bc       = (float*)(ws + 69 * MB + 512 * 1024);  // 512 KB
    float*          dbuf     = (float*)(ws + 70 * MB);               // 32 MB fp32 delta
    unsigned short* ybf      = (unsigned short*)(ws + 102 * MB);     // 16 MB
    float*          h0       = (float*)(ws + 118 * MB);              //  8 MB   (126 MB total)
    // region [48,64) MB reused after in-proj GEMM:
    float* Ppart = (float*)xnorm_bf;   // 16 MB split-K partials
    float* P     = (float*)xnorm_bf;   //  8 MB (after reduce)
    float* Hb    = (float*)wt_in;      //  8 MB
    float* hlast = out + (size_t)MM * DM;

    dim3 tb(32, 8);
    rmsnorm_bf16<<<MM, 256, 0, stream>>>(hidden, norm_w, xnorm_bf);
    transpose_f2bf<<<dim3(4096/32, 1024/32), tb, 0, stream>>>(W_in, wt_in, 1024, 4096);
    transpose_f2bf<<<dim3(3, 2048/32), tb, 0, stream>>>(W_x, wt_x, 2048, 96);
    transpose_f2bf<<<dim3(2048/32, 2), tb, 0, stream>>>(W_dt, wt_dt, 64, 2048);
    transpose_f2bf<<<dim3(1024/32, 2048/32), tb, 0, stream>>>(W_out, wt_out, 2048, 1024);

    // xzb = bf16( rmsnorm(x) @ W_in )   (M=4096, N=4096, K=1024)
    gemm_mfma<4><<<dim3(32, 32), 256, 0, stream>>>(xnorm_bf, wt_in, nullptr, nullptr, xzb,
                                                   MM, 4096, 1024, 4096);
    // x_act = silu(dwconv(x_in))  (bf16)
    conv_silu<<<(MM * EI) / 256, 256, 0, stream>>>(xzb, conv_w, xact_bf);
    // x_db partials = x_act @ W_x, split-K over 8 slices (M=4096, N=128pad, K=2048)
    gemm_mfma<3><<<dim3(8, 32), 256, 0, stream>>>(xact_bf, wt_x, Ppart, nullptr, nullptr,
                                                  MM, 128, 2048, 128);
    xproj_reduce<<<(MM * 128) / 256, 256, 0, stream>>>(Ppart, dtlr, bc);
    // delta = softplus(dtlr @ W_dt + b_dt)   (M=4096, N=2048, K=64) -> fp32 dbuf
    gemm_mfma<2><<<dim3(16, 32), 256, 0, stream>>>(dtlr, wt_dt, dbuf, b_dt, nullptr,
                                                   MM, 2048, 64, 2048);
    // chunked selective scan
    scan_phase1<<<dim3(8, NCHUNK, BB), 256, 0, stream>>>(dbuf, xact_bf, bc, A_log, P, Hb);
    scan_phase2<<<(BB * NS * EI) / 256, 256, 0, stream>>>(P, Hb, h0, hlast);
    scan_phase3<<<dim3(8, NCHUNK, BB), 256, 0, stream>>>(dbuf, xact_bf, xzb, bc, A_log, D_par, h0, ybf);
    // out = residual + y @ W_out  (M=4096, N=1024, K=2048)
    gemm_mfma<1><<<dim3(8, 32), 256, 0, stream>>>(ybf, wt_out, out, hidden, nullptr,
                                                  MM, 1024, 2048, 1024);
}

// Round 3
// 331.703 us; speedup vs baseline: 1.2956x; 1.0597x over previous
//
#include <hip/hip_runtime.h>
#include <cstdint>
#include <cstddef>

// Problem constants (B=4, L=1024)
#define DM 1024      // D_MODEL
#define EI 2048      // E_INNER
#define NS 16        // N_STATE
#define DR 64        // DT_RANK
#define BB 4
#define LL 1024
#define MM (BB*LL)   // 4096 token rows
#define NCHUNK 32
#define CHUNK 32

typedef __attribute__((ext_vector_type(8))) __bf16 bf16x8;
typedef __attribute__((ext_vector_type(4))) float f32x4;
typedef __attribute__((ext_vector_type(8))) unsigned short u16x8;

__device__ __forceinline__ unsigned short f2bf(float f) {
    union { float f; unsigned int u; } v; v.f = f;
    unsigned int r = v.u + 0x7FFFu + ((v.u >> 16) & 1u);   // RNE
    return (unsigned short)(r >> 16);
}
__device__ __forceinline__ float bf2f(unsigned short u) {
    union { unsigned int u; float f; } v; v.u = ((unsigned int)u) << 16;
    return v.f;
}

__device__ __forceinline__ void gload_lds16(const unsigned short* g, unsigned short* l) {
    __builtin_amdgcn_global_load_lds(
        (const __attribute__((address_space(1))) unsigned int*)g,
        (__attribute__((address_space(3))) unsigned int*)l, 16, 0, 0);
}

// ---------------- RMSNorm -> bf16 ----------------
__global__ void rmsnorm_bf16(const float* __restrict__ x, const float* __restrict__ w,
                             unsigned short* __restrict__ out) {
    int m = blockIdx.x, tid = threadIdx.x;
    const float4* row = (const float4*)(x + (size_t)m * DM);
    float4 v = row[tid];
    float ss = v.x*v.x + v.y*v.y + v.z*v.z + v.w*v.w;
    #pragma unroll
    for (int o = 32; o; o >>= 1) ss += __shfl_down(ss, o);
    __shared__ float red[4];
    if ((tid & 63) == 0) red[tid >> 6] = ss;
    __syncthreads();
    ss = red[0] + red[1] + red[2] + red[3];
    float scale = rsqrtf(ss * (1.0f / DM) + 1e-6f);
    const float4* wr = (const float4*)w;
    float4 wv = wr[tid];
    ushort4 o4;
    o4.x = f2bf(v.x * scale * wv.x);
    o4.y = f2bf(v.y * scale * wv.y);
    o4.z = f2bf(v.z * scale * wv.z);
    o4.w = f2bf(v.w * scale * wv.w);
    ((ushort4*)out)[(size_t)m * (DM/4) + tid] = o4;
}

// ---------------- fused transpose fp32 (R,C) -> bf16 (Cpad,R) for all 4 weights ----------------
__global__ void transpose_all(const float* __restrict__ W_in, const float* __restrict__ W_x,
                              const float* __restrict__ W_dt, const float* __restrict__ W_out,
                              unsigned short* __restrict__ wt_in, unsigned short* __restrict__ wt_x,
                              unsigned short* __restrict__ wt_dt, unsigned short* __restrict__ wt_out) {
    __shared__ float t[32][33];
    int id = blockIdx.x;
    const float* in; unsigned short* out;
    int R, C, Cpad, bx, by;
    if (id < 4096)      { in = W_in;  out = wt_in;  R = 1024; C = 4096; Cpad = 4096; bx = id & 127; by = id >> 7; }
    else if (id < 4352) { id -= 4096; in = W_x;  out = wt_x;  R = 2048; C = 96;  Cpad = 128;  bx = id & 3;  by = id >> 2; }
    else if (id < 4480) { id -= 4352; in = W_dt; out = wt_dt; R = 64;   C = 2048; Cpad = 2048; bx = id & 63; by = id >> 6; }
    else                { id -= 4480; in = W_out; out = wt_out; R = 2048; C = 1024; Cpad = 1024; bx = id & 31; by = id >> 5; }
    int c0 = bx * 32, r0 = by * 32;
    int tx = threadIdx.x, ty = threadIdx.y;
    #pragma unroll
    for (int j = 0; j < 32; j += 8) {
        int r = r0 + ty + j, c = c0 + tx;
        t[ty + j][tx] = (r < R && c < C) ? in[(size_t)r * C + c] : 0.f;
    }
    __syncthreads();
    #pragma unroll
    for (int j = 0; j < 32; j += 8) {
        int c = c0 + ty + j, r = r0 + tx;
        if (c < Cpad && r < R) out[(size_t)c * R + r] = f2bf(t[tx][ty + j]);
    }
}

// ---------------- MFMA GEMM: C[M,N] = A[M,K](bf16) * Bt[N,K](bf16)^T ----------------
// EPI 1: fp32 store + residual             (out-proj)
// EPI 2: bf16 store softplus(v+bias)       (delta-proj)
// EPI 3: split-K partial fp32, grid.x = 8 k-slices, single 128-wide N tile (x-proj)
// EPI 4: bf16 store                        (in-proj)
template<int EPI>
__global__ void gemm_mfma(const unsigned short* __restrict__ A,
                          const unsigned short* __restrict__ Bt,
                          float* __restrict__ C,
                          const float* __restrict__ ex1,
                          unsigned short* __restrict__ exb,
                          int M, int N, int K, int ldc) {
    __shared__ __attribute__((aligned(16))) unsigned short lds_a[128 * 32];
    __shared__ __attribute__((aligned(16))) unsigned short lds_b[128 * 32];
    const int tid = threadIdx.x;
    const int w = tid >> 6, lane = tid & 63;
    const int m0 = blockIdx.y * 128;
    const int n0 = (EPI == 3) ? 0 : blockIdx.x * 128;
    const int kstart = (EPI == 3) ? blockIdx.x * (K >> 3) : 0;
    const int kend   = (EPI == 3) ? kstart + (K >> 3) : K;
    const int wm = (w & 1) * 64, wn = (w >> 1) * 64;
    const int q = lane >> 4, r = lane & 15;
    const int srow = lane >> 2;          // 0..15
    const int scol = (lane & 3) * 8;     // 0,8,16,24

    f32x4 acc[4][4];
    f32x4 zero = {0.f, 0.f, 0.f, 0.f};
    #pragma unroll
    for (int i = 0; i < 4; ++i)
        #pragma unroll
        for (int j = 0; j < 4; ++j) acc[i][j] = zero;

    for (int kb = kstart; kb < kend; kb += 32) {
        __syncthreads();
        #pragma unroll
        for (int j = 0; j < 2; ++j) {
            int rbase = w * 32 + j * 16;
            gload_lds16(A  + (size_t)(m0 + rbase + srow) * K + kb + scol, lds_a + rbase * 32);
            gload_lds16(Bt + (size_t)(n0 + rbase + srow) * K + kb + scol, lds_b + rbase * 32);
        }
        __syncthreads();
        bf16x8 af[4], bfr[4];
        #pragma unroll
        for (int mi = 0; mi < 4; ++mi)
            af[mi] = *(const bf16x8*)(lds_a + (wm + mi * 16 + r) * 32 + q * 8);
        #pragma unroll
        for (int ni = 0; ni < 4; ++ni)
            bfr[ni] = *(const bf16x8*)(lds_b + (wn + ni * 16 + r) * 32 + q * 8);
        #pragma unroll
        for (int mi = 0; mi < 4; ++mi)
            #pragma unroll
            for (int ni = 0; ni < 4; ++ni)
                acc[mi][ni] = __builtin_amdgcn_mfma_f32_16x16x32_bf16(af[mi], bfr[ni], acc[mi][ni], 0, 0, 0);
    }

    #pragma unroll
    for (int mi = 0; mi < 4; ++mi) {
        #pragma unroll
        for (int ni = 0; ni < 4; ++ni) {
            f32x4 v = acc[mi][ni];
            int gmb = m0 + wm + mi * 16 + q * 4;
            int gn  = n0 + wn + ni * 16 + r;
            #pragma unroll
            for (int t = 0; t < 4; ++t) {
                int gm = gmb + t;
                float val = v[t];
                if (EPI == 1) {
                    C[(size_t)gm * ldc + gn] = val + ex1[(size_t)gm * ldc + gn];
                } else if (EPI == 2) {
                    val += ex1[gn];
                    val = fmaxf(val, 0.f) + log1pf(__expf(-fabsf(val)));
                    exb[(size_t)gm * ldc + gn] = f2bf(val);
                } else if (EPI == 3) {
                    C[((size_t)blockIdx.x * M + gm) * 128 + gn] = val;
                } else {
                    exb[(size_t)gm * ldc + gn] = f2bf(val);
                }
            }
        }
    }
}

// ---------------- split-K reduce for x-proj: sum 8 partials, split dtlr/bc ----------------
__global__ void xproj_reduce(const float* __restrict__ Pp,
                             unsigned short* __restrict__ dtlr, float* __restrict__ bc) {
    int id = blockIdx.x * 256 + threadIdx.x;   // 4096*128
    int n = id & 127, m = id >> 7;
    if (n >= DR + 2 * NS) return;
    float s = 0.f;
    #pragma unroll
    for (int ks = 0; ks < 8; ++ks)
        s += Pp[((size_t)ks * MM + m) * 128 + n];
    if (n < DR) dtlr[(size_t)m * DR + n] = f2bf(s);
    else bc[(size_t)m * 32 + (n - DR)] = s;
}

// ---------------- causal depthwise conv(K=4) + SiLU, 8 elements/thread ----------------
__global__ void conv_silu8(const unsigned short* __restrict__ xzb, const float* __restrict__ cw,
                           unsigned short* __restrict__ xab) {
    size_t idx8 = ((size_t)blockIdx.x * 256 + threadIdx.x) * 8;   // m*2048 + e
    int e = (int)(idx8 & (EI - 1));
    size_t m = idx8 >> 11;
    int l = (int)(m & (LL - 1));
    u16x8 x0 = *(const u16x8*)(xzb + m * 4096 + e);
    u16x8 zer = {0,0,0,0,0,0,0,0};
    u16x8 x1 = (l >= 1) ? *(const u16x8*)(xzb + (m - 1) * 4096 + e) : zer;
    u16x8 x2 = (l >= 2) ? *(const u16x8*)(xzb + (m - 2) * 4096 + e) : zer;
    u16x8 x3 = (l >= 3) ? *(const u16x8*)(xzb + (m - 3) * 4096 + e) : zer;
    u16x8 o;
    #pragma unroll
    for (int j = 0; j < 8; ++j) {
        float4 wv = ((const float4*)cw)[e + j];   // {w0,w1,w2,w3} for channel e+j
        float s = bf2f(x0[j]) * wv.w + bf2f(x1[j]) * wv.z
                + bf2f(x2[j]) * wv.y + bf2f(x3[j]) * wv.x;
        float a = s / (1.f + __expf(-s));
        o[j] = f2bf(a);
    }
    *(u16x8*)(xab + idx8) = o;
}

// ---------------- selective scan, 3-phase chunked (CHUNK=32, NCHUNK=32) ----------------
__global__ void scan_phase1(const unsigned short* __restrict__ dbufb, const unsigned short* __restrict__ xu,
                            const float* __restrict__ bc, const float* __restrict__ A_log,
                            float* __restrict__ P, float* __restrict__ H) {
    int e = blockIdx.x * 256 + threadIdx.x;
    int c = blockIdx.y, b = blockIdx.z;
    float A[NS], h[NS], p[NS];
    #pragma unroll
    for (int n = 0; n < NS; ++n) {
        A[n] = -expf(A_log[(size_t)e * NS + n]);
        h[n] = 0.f; p[n] = 1.f;
    }
    int mbase = b * LL + c * CHUNK;
    for (int t = 0; t < CHUNK; ++t) {
        size_t m = (size_t)(mbase + t);
        float d = bf2f(dbufb[m * 2048 + e]);
        float u = bf2f(xu[m * 2048 + e]);
        float du = d * u;
        const float* Bv = bc + m * 32;
        #pragma unroll
        for (int n = 0; n < NS; ++n) {
            float dA = __expf(d * A[n]);
            p[n] *= dA;
            h[n] = fmaf(dA, h[n], du * Bv[n]);
        }
    }
    size_t base = ((size_t)(b * NCHUNK + c) * NS) * 2048 + e;
    #pragma unroll
    for (int n = 0; n < NS; ++n) {
        P[base + (size_t)n * 2048] = p[n];
        H[base + (size_t)n * 2048] = h[n];
    }
}

// one thread per (b,n,e): coalesced over e
__global__ void scan_phase2(const float* __restrict__ P, const float* __restrict__ H,
                            float* __restrict__ h0, float* __restrict__ hlast) {
    int id = blockIdx.x * 256 + threadIdx.x;
    int e = id & (EI - 1);
    int bn = id >> 11;
    int n = bn & (NS - 1), b = bn >> 4;
    float h = 0.f;
    #pragma unroll
    for (int c = 0; c < NCHUNK; ++c) {
        size_t ix = (((size_t)(b * NCHUNK + c) * NS) + n) * 2048 + e;
        h0[ix] = h;
        h = fmaf(P[ix], h, H[ix]);
    }
    hlast[(((size_t)b * EI + e) * NS) + n] = h;
}

__global__ void scan_phase3(const unsigned short* __restrict__ dbufb, const unsigned short* __restrict__ xu,
                            const unsigned short* __restrict__ xzb,
                            const float* __restrict__ bc, const float* __restrict__ A_log,
                            const float* __restrict__ Dp, const float* __restrict__ h0,
                            unsigned short* __restrict__ ybf) {
    int e = blockIdx.x * 256 + threadIdx.x;
    int c = blockIdx.y, b = blockIdx.z;
    float A[NS], h[NS];
    size_t base = ((size_t)(b * NCHUNK + c) * NS) * 2048 + e;
    #pragma unroll
    for (int n = 0; n < NS; ++n) {
        A[n] = -expf(A_log[(size_t)e * NS + n]);
        h[n] = h0[base + (size_t)n * 2048];
    }
    float D = Dp[e];
    int mbase = b * LL + c * CHUNK;
    for (int t = 0; t < CHUNK; ++t) {
        size_t m = (size_t)(mbase + t);
        float d = bf2f(dbufb[m * 2048 + e]);
        float u = bf2f(xu[m * 2048 + e]);
        float du = d * u;
        const float* Bv = bc + m * 32;
        float y = 0.f;
        #pragma unroll
        for (int n = 0; n < NS; ++n) {
            float dA = __expf(d * A[n]);
            h[n] = fmaf(dA, h[n], du * Bv[n]);
            y = fmaf(h[n], Bv[16 + n], y);
        }
        y = fmaf(u, D, y);
        float z = bf2f(xzb[m * 4096 + 2048 + e]);
        float sil = z / (1.f + __expf(-z));
        ybf[m * 2048 + e] = f2bf(y * sil);
    }
}

extern "C" void kernel_launch(void* const* d_in, const int* in_sizes, int n_in,
                              void* d_out, int out_size, void* d_ws, size_t ws_size,
                              hipStream_t stream) {
    (void)in_sizes; (void)n_in; (void)out_size; (void)ws_size;
    const float* hidden = (const float*)d_in[0];
    const float* norm_w = (const float*)d_in[1];
    const float* W_in   = (const float*)d_in[2];
    const float* conv_w = (const float*)d_in[3];
    const float* W_x    = (const float*)d_in[4];
    const float* W_dt   = (const float*)d_in[5];
    const float* b_dt   = (const float*)d_in[6];
    const float* A_log  = (const float*)d_in[7];
    const float* D_par  = (const float*)d_in[8];
    const float* W_out  = (const float*)d_in[9];
    float* out = (float*)d_out;
    char* ws = (char*)d_ws;
    const size_t MB = 1ull << 20;

    unsigned short* xzb      = (unsigned short*)(ws + 0);            // 32 MB bf16 (x_in|z)
    unsigned short* xact_bf  = (unsigned short*)(ws + 32 * MB);      // 16 MB
    unsigned short* xnorm_bf = (unsigned short*)(ws + 48 * MB);      //  8 MB
    unsigned short* wt_in    = (unsigned short*)(ws + 56 * MB);      //  8 MB
    unsigned short* wt_out   = (unsigned short*)(ws + 64 * MB);      //  4 MB
    unsigned short* wt_x     = (unsigned short*)(ws + 68 * MB);      // 512 KB (padded 96->128 rows)
    unsigned short* wt_dt    = (unsigned short*)(ws + 68 * MB + 512 * 1024);  // 256 KB
    unsigned short* dtlr     = (unsigned short*)(ws + 69 * MB);      // 512 KB
    float*          bc       = (float*)(ws + 69 * MB + 512 * 1024);  // 512 KB
    unsigned short* dbufb    = (unsigned short*)(ws + 70 * MB);      // 16 MB bf16 delta
    unsigned short* ybf      = (unsigned short*)(ws + 86 * MB);      // 16 MB
    float*          h0       = (float*)(ws + 102 * MB);              // 16 MB
    float*          P        = (float*)(ws + 118 * MB);              // 16 MB
    float*          Hb       = (float*)(ws + 134 * MB);              // 16 MB  (150 MB total)
    float* Ppart = P;                    // 16 MB split-K partials (dead before scan)
    float* hlast = out + (size_t)MM * DM;

    rmsnorm_bf16<<<MM, 256, 0, stream>>>(hidden, norm_w, xnorm_bf);
    transpose_all<<<6528, dim3(32, 8), 0, stream>>>(W_in, W_x, W_dt, W_out,
                                                    wt_in, wt_x, wt_dt, wt_out);

    // xzb = bf16( rmsnorm(x) @ W_in )   (M=4096, N=4096, K=1024)
    gemm_mfma<4><<<dim3(32, 32), 256, 0, stream>>>(xnorm_bf, wt_in, nullptr, nullptr, xzb,
                                                   MM, 4096, 1024, 4096);
    // x_act = silu(dwconv(x_in))  (bf16)
    conv_silu8<<<(MM * EI) / (256 * 8), 256, 0, stream>>>(xzb, conv_w, xact_bf);
    // x_db partials = x_act @ W_x, split-K over 8 slices (M=4096, N=128pad, K=2048)
    gemm_mfma<3><<<dim3(8, 32), 256, 0, stream>>>(xact_bf, wt_x, Ppart, nullptr, nullptr,
                                                  MM, 128, 2048, 128);
    xproj_reduce<<<(MM * 128) / 256, 256, 0, stream>>>(Ppart, dtlr, bc);
    // delta = bf16( softplus(dtlr @ W_dt + b_dt) )   (M=4096, N=2048, K=64)
    gemm_mfma<2><<<dim3(16, 32), 256, 0, stream>>>(dtlr, wt_dt, nullptr, b_dt, dbufb,
                                                   MM, 2048, 64, 2048);
    // chunked selective scan
    scan_phase1<<<dim3(8, NCHUNK, BB), 256, 0, stream>>>(dbufb, xact_bf, bc, A_log, P, Hb);
    scan_phase2<<<(BB * NS * EI) / 256, 256, 0, stream>>>(P, Hb, h0, hlast);
    scan_phase3<<<dim3(8, NCHUNK, BB), 256, 0, stream>>>(dbufb, xact_bf, xzb, bc, A_log, D_par, h0, ybf);
    // out = residual + y @ W_out  (M=4096, N=1024, K=2048)
    gemm_mfma<1><<<dim3(8, 32), 256, 0, stream>>>(ybf, wt_out, out, hidden, nullptr,
                                                  MM, 1024, 2048, 1024);
}